// Round 1
// baseline (438.545 us; speedup 1.0000x reference)
//
#include <hip/hip_runtime.h>
#include <math.h>

// B=batch, S=state_dim, D=image channels, N=spatial positions
#define BB 128
#define SS 1024
#define DD 512
#define NN 784
#define NCH 8        // d-chunks for logit partials

__device__ __forceinline__ float wave_reduce_sum(float x) {
#pragma unroll
  for (int m = 32; m > 0; m >>= 1) x += __shfl_xor(x, m, 64);
  return x;
}
__device__ __forceinline__ float wave_reduce_max(float x) {
#pragma unroll
  for (int m = 32; m > 0; m >>= 1) x = fmaxf(x, __shfl_xor(x, m, 64));
  return x;
}

// K1: v[k] = sum_j Wa[j] * Wc[j, k],  k in [0, 2D).  v pre-zeroed by memsetAsync.
// grid (4 k-blocks, 16 j-chunks), block 256
__global__ void k1_v(const float* __restrict__ Wa, const float* __restrict__ Wc,
                     float* __restrict__ v) {
  int k = blockIdx.x * 256 + threadIdx.x;
  int j0 = blockIdx.y * 32;
  float acc = 0.f;
#pragma unroll
  for (int j = 0; j < 32; ++j)
    acc += Wa[j0 + j] * Wc[(size_t)(j0 + j) * (2 * DD) + k];
  atomicAdd(&v[k], acc);
}

// K2: w[b,d] = (in_state[b,:]·Wq[d,:] + bq[d]) * v[d] + v[D+d]
// grid (4 d-chunks, B), block 256 (4 waves x 32 rows), wave-per-row dot
__global__ void k2_w(const float* __restrict__ in_state, const float* __restrict__ Wq,
                     const float* __restrict__ bq, const float* __restrict__ v,
                     float* __restrict__ w) {
  __shared__ float st[SS];
  int b = blockIdx.y;
  int t = threadIdx.x, lane = t & 63, wv = t >> 6;
  ((float4*)st)[t] = ((const float4*)(in_state + (size_t)b * SS))[t];
  __syncthreads();
  const float4* st4 = (const float4*)st;
  int dbase = blockIdx.x * 128 + wv * 32;
  for (int r = 0; r < 32; ++r) {
    int d = dbase + r;
    const float4* q4 = (const float4*)(Wq + (size_t)d * SS);
    float acc = 0.f;
#pragma unroll
    for (int j = 0; j < 4; ++j) {
      float4 a = q4[lane + 64 * j];
      float4 s = st4[lane + 64 * j];
      acc += a.x * s.x + a.y * s.y + a.z * s.z + a.w * s.w;
    }
    acc = wave_reduce_sum(acc);
    if (lane == 0) w[(size_t)b * DD + d] = (acc + bq[d]) * v[d] + v[DD + d];
  }
}

// K3: part[b,c,n] = sum over d-chunk c (64 rows) of image[b,d,n] * w[b,d]
// grid (NCH, B), block 256 (4 waves x 16 rows). Lane accumulates 784/4=196
// float4 columns: j=0..2 full wave, j=3 lanes 0..3.
__global__ void k3_logit_part(const float* __restrict__ image, const float* __restrict__ w,
                              float* __restrict__ part) {
  __shared__ float wl[64];
  __shared__ float red[4 * NN];
  int b = blockIdx.y, c = blockIdx.x;
  int t = threadIdx.x, lane = t & 63, wv = t >> 6;
  if (t < 64) wl[t] = w[(size_t)b * DD + c * 64 + t];
  __syncthreads();
  float4 a0 = {0, 0, 0, 0}, a1 = {0, 0, 0, 0}, a2 = {0, 0, 0, 0}, a3 = {0, 0, 0, 0};
  int d0 = c * 64 + wv * 16;
  for (int r = 0; r < 16; ++r) {
    float wd = wl[wv * 16 + r];
    const float4* row4 = (const float4*)(image + ((size_t)b * DD + (d0 + r)) * NN);
    float4 x0 = row4[lane];
    float4 x1 = row4[lane + 64];
    float4 x2 = row4[lane + 128];
    a0.x += x0.x * wd; a0.y += x0.y * wd; a0.z += x0.z * wd; a0.w += x0.w * wd;
    a1.x += x1.x * wd; a1.y += x1.y * wd; a1.z += x1.z * wd; a1.w += x1.w * wd;
    a2.x += x2.x * wd; a2.y += x2.y * wd; a2.z += x2.z * wd; a2.w += x2.w * wd;
    if (lane < 4) {
      float4 x3 = row4[lane + 192];
      a3.x += x3.x * wd; a3.y += x3.y * wd; a3.z += x3.z * wd; a3.w += x3.w * wd;
    }
  }
  float4* red4 = (float4*)(red + wv * NN);
  red4[lane] = a0;
  red4[lane + 64] = a1;
  red4[lane + 128] = a2;
  if (lane < 4) red4[lane + 192] = a3;
  __syncthreads();
  float* out = part + ((size_t)b * NCH + c) * NN;
  for (int n = t; n < NN; n += 256)
    out[n] = red[n] + red[NN + n] + red[2 * NN + n] + red[3 * NN + n];
}

// K4: reduce NCH partials -> logits, softmax over n -> attn[b,n]
// grid (B), block 256
__global__ void k4_softmax(const float* __restrict__ part, float* __restrict__ attn) {
  __shared__ float l[NN];
  __shared__ float wred[4];
  int b = blockIdx.x, t = threadIdx.x, lane = t & 63, wv = t >> 6;
  const float* p = part + (size_t)b * NCH * NN;
  float mx = -1e30f;
  for (int n = t; n < NN; n += 256) {
    float s = 0.f;
#pragma unroll
    for (int c = 0; c < NCH; ++c) s += p[c * NN + n];
    l[n] = s;
    mx = fmaxf(mx, s);
  }
  mx = wave_reduce_max(mx);
  if (lane == 0) wred[wv] = mx;
  __syncthreads();
  mx = fmaxf(fmaxf(wred[0], wred[1]), fmaxf(wred[2], wred[3]));
  __syncthreads();
  float sum = 0.f;
  for (int n = t; n < NN; n += 256) {
    float e = __expf(l[n] - mx);
    l[n] = e;
    sum += e;
  }
  sum = wave_reduce_sum(sum);
  if (lane == 0) wred[wv] = sum;
  __syncthreads();
  float inv = 1.0f / (wred[0] + wred[1] + wred[2] + wred[3]);
  float* a = attn + (size_t)b * NN;
  for (int n = t; n < NN; n += 256) a[n] = l[n] * inv;
}

// K5: pooled[b,d] = sum_n attn[b,n] * image[b,d,n]
// grid (32 d-chunks, B), block 256 (4 waves x 4 rows), wave-per-row dot
__global__ void k5_pooled(const float* __restrict__ image, const float* __restrict__ attn,
                          float* __restrict__ pooled) {
  __shared__ float a_s[NN];
  int b = blockIdx.y, t = threadIdx.x, lane = t & 63, wv = t >> 6;
  for (int n = t; n < NN; n += 256) a_s[n] = attn[(size_t)b * NN + n];
  __syncthreads();
  const float4* a4 = (const float4*)a_s;
  int d0 = blockIdx.x * 16 + wv * 4;
  for (int r = 0; r < 4; ++r) {
    int d = d0 + r;
    const float4* row4 = (const float4*)(image + ((size_t)b * DD + d) * NN);
    float acc = 0.f;
#pragma unroll
    for (int j = 0; j < 3; ++j) {
      float4 x = row4[lane + 64 * j];
      float4 aa = a4[lane + 64 * j];
      acc += x.x * aa.x + x.y * aa.y + x.z * aa.z + x.w * aa.w;
    }
    if (lane < 4) {
      float4 x = row4[lane + 192];
      float4 aa = a4[lane + 192];
      acc += x.x * aa.x + x.y * aa.y + x.z * aa.z + x.w * aa.w;
    }
    acc = wave_reduce_sum(acc);
    if (lane == 0) pooled[(size_t)b * DD + d] = acc;
  }
}

// K6: out[b,s] = pooled[b,:]·Wo[s,:] + bo[s]
// grid (16 s-chunks, B), block 256 (4 waves x 16 rows)
__global__ void k6_out(const float* __restrict__ pooled, const float* __restrict__ Wo,
                       const float* __restrict__ bo, float* __restrict__ out) {
  __shared__ float p_s[DD];
  int b = blockIdx.y, t = threadIdx.x, lane = t & 63, wv = t >> 6;
  ((float2*)p_s)[t] = ((const float2*)(pooled + (size_t)b * DD))[t];
  __syncthreads();
  const float4* p4 = (const float4*)p_s;
  int s0 = blockIdx.x * 64 + wv * 16;
  for (int r = 0; r < 16; ++r) {
    int s = s0 + r;
    const float4* wo4 = (const float4*)(Wo + (size_t)s * DD);
    float acc = 0.f;
#pragma unroll
    for (int j = 0; j < 2; ++j) {
      float4 x = wo4[lane + 64 * j];
      float4 pp = p4[lane + 64 * j];
      acc += x.x * pp.x + x.y * pp.y + x.z * pp.z + x.w * pp.w;
    }
    acc = wave_reduce_sum(acc);
    if (lane == 0) out[(size_t)b * SS + s] = acc + bo[s];
  }
}

extern "C" void kernel_launch(void* const* d_in, const int* in_sizes, int n_in,
                              void* d_out, int out_size, void* d_ws, size_t ws_size,
                              hipStream_t stream) {
  const float* in_state = (const float*)d_in[0];
  const float* image    = (const float*)d_in[1];
  const float* Wq       = (const float*)d_in[2];
  const float* bq       = (const float*)d_in[3];
  // d_in[4] = Wc used only through v; d_in[5] = bc and d_in[7] = ba are
  // softmax-invariant constants on the logits -> dropped.
  const float* Wc       = (const float*)d_in[4];
  const float* Wa       = (const float*)d_in[6];
  const float* Wo       = (const float*)d_in[8];
  const float* bo       = (const float*)d_in[9];
  float* out = (float*)d_out;

  // workspace layout (floats): total ~4.14 MB
  float* ws     = (float*)d_ws;
  float* v      = ws;                       // 2D            = 1024
  float* w      = v + 2 * DD;               // B*D           = 65536
  float* part   = w + BB * DD;              // B*NCH*N       = 802816
  float* attn   = part + (size_t)BB * NCH * NN;  // B*N      = 100352
  float* pooled = attn + (size_t)BB * NN;   // B*D           = 65536

  hipMemsetAsync(v, 0, 2 * DD * sizeof(float), stream);
  k1_v<<<dim3(4, 16), 256, 0, stream>>>(Wa, Wc, v);
  k2_w<<<dim3(4, BB), 256, 0, stream>>>(in_state, Wq, bq, v, w);
  k3_logit_part<<<dim3(NCH, BB), 256, 0, stream>>>(image, w, part);
  k4_softmax<<<BB, 256, 0, stream>>>(part, attn);
  k5_pooled<<<dim3(32, BB), 256, 0, stream>>>(image, attn, pooled);
  k6_out<<<dim3(16, BB), 256, 0, stream>>>(pooled, Wo, bo, out);
}

// Round 2
// 379.791 us; speedup vs baseline: 1.1547x; 1.1547x over previous
//
#include <hip/hip_runtime.h>
#include <math.h>

// B=batch, S=state_dim, D=image channels, N=spatial positions
#define BB 128
#define SS 1024
#define DD 512
#define NN 784
#define NCH 8        // d-chunks for logit partials

__device__ __forceinline__ float wave_reduce_sum(float x) {
#pragma unroll
  for (int m = 32; m > 0; m >>= 1) x += __shfl_xor(x, m, 64);
  return x;
}
__device__ __forceinline__ float wave_reduce_max(float x) {
#pragma unroll
  for (int m = 32; m > 0; m >>= 1) x = fmaxf(x, __shfl_xor(x, m, 64));
  return x;
}

// K1: v[k] = sum_j Wa[j] * Wc[j, k],  k in [0, 2D).  v pre-zeroed by memsetAsync.
// grid (4 k-blocks, 16 j-chunks), block 256
__global__ void k1_v(const float* __restrict__ Wa, const float* __restrict__ Wc,
                     float* __restrict__ v) {
  int k = blockIdx.x * 256 + threadIdx.x;
  int j0 = blockIdx.y * 32;
  float acc = 0.f;
#pragma unroll
  for (int j = 0; j < 32; ++j)
    acc += Wa[j0 + j] * Wc[(size_t)(j0 + j) * (2 * DD) + k];
  atomicAdd(&v[k], acc);
}

// K2: w[b,d] = (in_state[b,:]·Wq[d,:] + bq[d]) * v[d] + v[D+d]
// grid (16 d-chunks, B) = 2048 blocks, block 256 (4 waves x 8 rows).
// All 32 row-loads issued before any reduce; state fragment hoisted to regs.
__global__ void k2_w(const float* __restrict__ in_state, const float* __restrict__ Wq,
                     const float* __restrict__ bq, const float* __restrict__ v,
                     float* __restrict__ w) {
  __shared__ float st[SS];
  int b = blockIdx.y;
  int t = threadIdx.x, lane = t & 63, wv = t >> 6;
  ((float4*)st)[t] = ((const float4*)(in_state + (size_t)b * SS))[t];
  __syncthreads();
  const float4* st4 = (const float4*)st;
  float4 s0 = st4[lane], s1 = st4[lane + 64], s2 = st4[lane + 128], s3 = st4[lane + 192];
  int d0 = blockIdx.x * 32 + wv * 8;
  float acc[8];
#pragma unroll
  for (int r = 0; r < 8; ++r) {
    const float4* q4 = (const float4*)(Wq + (size_t)(d0 + r) * SS);
    float4 a0 = q4[lane], a1 = q4[lane + 64], a2 = q4[lane + 128], a3 = q4[lane + 192];
    acc[r] = a0.x * s0.x + a0.y * s0.y + a0.z * s0.z + a0.w * s0.w
           + a1.x * s1.x + a1.y * s1.y + a1.z * s1.z + a1.w * s1.w
           + a2.x * s2.x + a2.y * s2.y + a2.z * s2.z + a2.w * s2.w
           + a3.x * s3.x + a3.y * s3.y + a3.z * s3.z + a3.w * s3.w;
  }
#pragma unroll
  for (int r = 0; r < 8; ++r) acc[r] = wave_reduce_sum(acc[r]);
  if (lane == 0) {
#pragma unroll
    for (int r = 0; r < 8; ++r) {
      int d = d0 + r;
      w[(size_t)b * DD + d] = (acc[r] + bq[d]) * v[d] + v[DD + d];
    }
  }
}

// K3: part[b,c,n] = sum over d-chunk c (64 rows) of image[b,d,n] * w[b,d]
// grid (NCH, B) = 1024 blocks, block 512 (8 waves x 8 rows, fully unrolled:
// 24 independent main loads in flight per wave, w values in registers).
__global__ void k3_logit_part(const float* __restrict__ image, const float* __restrict__ w,
                              float* __restrict__ part) {
  __shared__ float red[8 * NN];   // 25088 B
  int b = blockIdx.y, c = blockIdx.x;
  int t = threadIdx.x, lane = t & 63, wv = t >> 6;
  int d0 = c * 64 + wv * 8;
  const float* wp = w + (size_t)b * DD + d0;
  float wr[8];
#pragma unroll
  for (int r = 0; r < 8; ++r) wr[r] = wp[r];   // broadcast loads (same addr per wave)
  const float4* base = (const float4*)(image + ((size_t)b * DD + d0) * NN);
  float4 a0 = {0, 0, 0, 0}, a1 = {0, 0, 0, 0}, a2 = {0, 0, 0, 0}, a3 = {0, 0, 0, 0};
#pragma unroll
  for (int r = 0; r < 8; ++r) {
    const float4* row4 = base + r * 196;
    float4 x0 = row4[lane];
    float4 x1 = row4[lane + 64];
    float4 x2 = row4[lane + 128];
    float wd = wr[r];
    a0.x += x0.x * wd; a0.y += x0.y * wd; a0.z += x0.z * wd; a0.w += x0.w * wd;
    a1.x += x1.x * wd; a1.y += x1.y * wd; a1.z += x1.z * wd; a1.w += x1.w * wd;
    a2.x += x2.x * wd; a2.y += x2.y * wd; a2.z += x2.z * wd; a2.w += x2.w * wd;
  }
  if (lane < 4) {
#pragma unroll
    for (int r = 0; r < 8; ++r) {
      float4 x3 = base[r * 196 + 192 + lane];
      float wd = wr[r];
      a3.x += x3.x * wd; a3.y += x3.y * wd; a3.z += x3.z * wd; a3.w += x3.w * wd;
    }
  }
  float4* red4 = (float4*)(red + wv * NN);
  red4[lane] = a0;
  red4[lane + 64] = a1;
  red4[lane + 128] = a2;
  if (lane < 4) red4[192 + lane] = a3;
  __syncthreads();
  float* out = part + ((size_t)b * NCH + c) * NN;
  for (int n = t; n < NN; n += 512) {
    float s = red[n] + red[NN + n] + red[2 * NN + n] + red[3 * NN + n]
            + red[4 * NN + n] + red[5 * NN + n] + red[6 * NN + n] + red[7 * NN + n];
    out[n] = s;
  }
}

// K4: reduce NCH partials -> logits, softmax over n -> attn[b,n]
// grid (B), block 256
__global__ void k4_softmax(const float* __restrict__ part, float* __restrict__ attn) {
  __shared__ float l[NN];
  __shared__ float wred[4];
  int b = blockIdx.x, t = threadIdx.x, lane = t & 63, wv = t >> 6;
  const float* p = part + (size_t)b * NCH * NN;
  float mx = -1e30f;
  for (int n = t; n < NN; n += 256) {
    float s = 0.f;
#pragma unroll
    for (int c = 0; c < NCH; ++c) s += p[c * NN + n];
    l[n] = s;
    mx = fmaxf(mx, s);
  }
  mx = wave_reduce_max(mx);
  if (lane == 0) wred[wv] = mx;
  __syncthreads();
  mx = fmaxf(fmaxf(wred[0], wred[1]), fmaxf(wred[2], wred[3]));
  __syncthreads();
  float sum = 0.f;
  for (int n = t; n < NN; n += 256) {
    float e = __expf(l[n] - mx);
    l[n] = e;
    sum += e;
  }
  sum = wave_reduce_sum(sum);
  if (lane == 0) wred[wv] = sum;
  __syncthreads();
  float inv = 1.0f / (wred[0] + wred[1] + wred[2] + wred[3]);
  float* a = attn + (size_t)b * NN;
  for (int n = t; n < NN; n += 256) a[n] = l[n] * inv;
}

// K5: pooled[b,d] = sum_n attn[b,n] * image[b,d,n]
// grid (16 d-chunks, B) = 2048 blocks, block 512 (8 waves x 4 rows, unrolled:
// 12 main loads in flight; attn fragment hoisted to regs; reduces at end).
__global__ void k5_pooled(const float* __restrict__ image, const float* __restrict__ attn,
                          float* __restrict__ pooled) {
  __shared__ float a_s[NN];
  int b = blockIdx.y, t = threadIdx.x, lane = t & 63, wv = t >> 6;
  if (t < 196) ((float4*)a_s)[t] = ((const float4*)(attn + (size_t)b * NN))[t];
  __syncthreads();
  const float4* a4 = (const float4*)a_s;
  float4 aa0 = a4[lane], aa1 = a4[lane + 64], aa2 = a4[lane + 128];
  int d0 = blockIdx.x * 32 + wv * 4;
  const float4* base = (const float4*)(image + ((size_t)b * DD + d0) * NN);
  float acc[4];
#pragma unroll
  for (int r = 0; r < 4; ++r) {
    const float4* row4 = base + r * 196;
    float4 x0 = row4[lane];
    float4 x1 = row4[lane + 64];
    float4 x2 = row4[lane + 128];
    acc[r] = x0.x * aa0.x + x0.y * aa0.y + x0.z * aa0.z + x0.w * aa0.w
           + x1.x * aa1.x + x1.y * aa1.y + x1.z * aa1.z + x1.w * aa1.w
           + x2.x * aa2.x + x2.y * aa2.y + x2.z * aa2.z + x2.w * aa2.w;
  }
  if (lane < 4) {
    float4 aa3 = a4[192 + lane];
#pragma unroll
    for (int r = 0; r < 4; ++r) {
      float4 x3 = base[r * 196 + 192 + lane];
      acc[r] += x3.x * aa3.x + x3.y * aa3.y + x3.z * aa3.z + x3.w * aa3.w;
    }
  }
#pragma unroll
  for (int r = 0; r < 4; ++r) acc[r] = wave_reduce_sum(acc[r]);
  if (lane == 0) {
#pragma unroll
    for (int r = 0; r < 4; ++r) pooled[(size_t)b * DD + d0 + r] = acc[r];
  }
}

// K6: out[b,s] = pooled[b,:]·Wo[s,:] + bo[s]
// grid (32 s-chunks, B) = 4096 blocks, block 256 (4 waves x 8 rows, unrolled)
__global__ void k6_out(const float* __restrict__ pooled, const float* __restrict__ Wo,
                       const float* __restrict__ bo, float* __restrict__ out) {
  __shared__ float p_s[DD];
  int b = blockIdx.y, t = threadIdx.x, lane = t & 63, wv = t >> 6;
  ((float2*)p_s)[t] = ((const float2*)(pooled + (size_t)b * DD))[t];
  __syncthreads();
  const float4* p4 = (const float4*)p_s;
  float4 p0 = p4[lane], p1 = p4[lane + 64];
  int s0 = blockIdx.x * 32 + wv * 8;
  float acc[8];
#pragma unroll
  for (int r = 0; r < 8; ++r) {
    const float4* wo4 = (const float4*)(Wo + (size_t)(s0 + r) * DD);
    float4 x0 = wo4[lane], x1 = wo4[lane + 64];
    acc[r] = x0.x * p0.x + x0.y * p0.y + x0.z * p0.z + x0.w * p0.w
           + x1.x * p1.x + x1.y * p1.y + x1.z * p1.z + x1.w * p1.w;
  }
#pragma unroll
  for (int r = 0; r < 8; ++r) acc[r] = wave_reduce_sum(acc[r]);
  if (lane == 0) {
#pragma unroll
    for (int r = 0; r < 8; ++r) out[(size_t)b * SS + s0 + r] = acc[r] + bo[s0 + r];
  }
}

extern "C" void kernel_launch(void* const* d_in, const int* in_sizes, int n_in,
                              void* d_out, int out_size, void* d_ws, size_t ws_size,
                              hipStream_t stream) {
  const float* in_state = (const float*)d_in[0];
  const float* image    = (const float*)d_in[1];
  const float* Wq       = (const float*)d_in[2];
  const float* bq       = (const float*)d_in[3];
  // d_in[4] = Wc used only through v; d_in[5] = bc and d_in[7] = ba are
  // softmax-invariant constants on the logits -> dropped.
  const float* Wc       = (const float*)d_in[4];
  const float* Wa       = (const float*)d_in[6];
  const float* Wo       = (const float*)d_in[8];
  const float* bo       = (const float*)d_in[9];
  float* out = (float*)d_out;

  // workspace layout (floats): total ~4.14 MB
  float* ws     = (float*)d_ws;
  float* v      = ws;                       // 2D            = 1024
  float* w      = v + 2 * DD;               // B*D           = 65536
  float* part   = w + BB * DD;              // B*NCH*N       = 802816
  float* attn   = part + (size_t)BB * NCH * NN;  // B*N      = 100352
  float* pooled = attn + (size_t)BB * NN;   // B*D           = 65536

  hipMemsetAsync(v, 0, 2 * DD * sizeof(float), stream);
  k1_v<<<dim3(4, 16), 256, 0, stream>>>(Wa, Wc, v);
  k2_w<<<dim3(16, BB), 256, 0, stream>>>(in_state, Wq, bq, v, w);
  k3_logit_part<<<dim3(NCH, BB), 512, 0, stream>>>(image, w, part);
  k4_softmax<<<BB, 256, 0, stream>>>(part, attn);
  k5_pooled<<<dim3(16, BB), 512, 0, stream>>>(image, attn, pooled);
  k6_out<<<dim3(32, BB), 256, 0, stream>>>(pooled, Wo, bo, out);
}

// Round 3
// 372.716 us; speedup vs baseline: 1.1766x; 1.0190x over previous
//
#include <hip/hip_runtime.h>
#include <math.h>

// B=batch, S=state_dim, D=image channels, N=spatial positions
#define BB 128
#define SS 1024
#define DD 512
#define NN 784
#define NCHK 4      // n-chunks per batch for fused split-softmax
#define NC 196      // n per chunk (= 49 float4)

__device__ __forceinline__ float wave_reduce_sum(float x) {
#pragma unroll
  for (int m = 32; m > 0; m >>= 1) x += __shfl_xor(x, m, 64);
  return x;
}
__device__ __forceinline__ float wave_reduce_max(float x) {
#pragma unroll
  for (int m = 32; m > 0; m >>= 1) x = fmaxf(x, __shfl_xor(x, m, 64));
  return x;
}

// K1: v[k] = sum_j Wa[j] * Wc[j, k],  k in [0, 2D).  v pre-zeroed by memsetAsync.
__global__ void k1_v(const float* __restrict__ Wa, const float* __restrict__ Wc,
                     float* __restrict__ v) {
  int k = blockIdx.x * 256 + threadIdx.x;
  int j0 = blockIdx.y * 32;
  float acc = 0.f;
#pragma unroll
  for (int j = 0; j < 32; ++j)
    acc += Wa[j0 + j] * Wc[(size_t)(j0 + j) * (2 * DD) + k];
  atomicAdd(&v[k], acc);
}

// K2: w[b,d] = (in_state[b,:]·Wq[d,:] + bq[d]) * v[d] + v[D+d]
// grid (16 d-chunks, B), block 256 (4 waves x 8 rows), loads before reduces.
__global__ void k2_w(const float* __restrict__ in_state, const float* __restrict__ Wq,
                     const float* __restrict__ bq, const float* __restrict__ v,
                     float* __restrict__ w) {
  __shared__ float st[SS];
  int b = blockIdx.y;
  int t = threadIdx.x, lane = t & 63, wv = t >> 6;
  ((float4*)st)[t] = ((const float4*)(in_state + (size_t)b * SS))[t];
  __syncthreads();
  const float4* st4 = (const float4*)st;
  float4 s0 = st4[lane], s1 = st4[lane + 64], s2 = st4[lane + 128], s3 = st4[lane + 192];
  int d0 = blockIdx.x * 32 + wv * 8;
  float acc[8];
#pragma unroll
  for (int r = 0; r < 8; ++r) {
    const float4* q4 = (const float4*)(Wq + (size_t)(d0 + r) * SS);
    float4 a0 = q4[lane], a1 = q4[lane + 64], a2 = q4[lane + 128], a3 = q4[lane + 192];
    acc[r] = a0.x * s0.x + a0.y * s0.y + a0.z * s0.z + a0.w * s0.w
           + a1.x * s1.x + a1.y * s1.y + a1.z * s1.z + a1.w * s1.w
           + a2.x * s2.x + a2.y * s2.y + a2.z * s2.z + a2.w * s2.w
           + a3.x * s3.x + a3.y * s3.y + a3.z * s3.z + a3.w * s3.w;
  }
#pragma unroll
  for (int r = 0; r < 8; ++r) acc[r] = wave_reduce_sum(acc[r]);
  if (lane == 0) {
#pragma unroll
    for (int r = 0; r < 8; ++r) {
      int d = d0 + r;
      w[(size_t)b * DD + d] = (acc[r] + bq[d]) * v[d] + v[DD + d];
    }
  }
}

// K3 fused: one (b, n-chunk) block sees all D rows for its 196 columns.
// Phase 1: chunk logits l_n = sum_d w[b,d]*img[b,d,n]  (HBM streaming read).
// Softmax-partial: m_c, Z_c, u_n = exp(l_n - m_c).
// Phase 2: P_c[d] = sum_{n in c} u_n*img[b,d,n]  (re-read chunk: L2/LLC hit).
// grid (NCHK, B) = 512 blocks, block 512 (8 waves x 64 d-rows each).
__global__ void k3_fused(const float* __restrict__ image, const float* __restrict__ w,
                         float* __restrict__ P_part, float* __restrict__ mZ_part) {
  __shared__ float w_lds[DD];
  __shared__ float4 red[8][49];
  __shared__ float4 u_lds[49];
  __shared__ float p_s[DD];
  int b = blockIdx.y, c = blockIdx.x;
  int t = threadIdx.x, lane = t & 63, wv = t >> 6;
  w_lds[t] = w[(size_t)b * DD + t];
  __syncthreads();
  const float4* img4 = (const float4*)image + (size_t)b * DD * 196;
  int d0 = wv * 64;
  const float4* pbase = img4 + (size_t)d0 * 196 + c * 49 + (lane < 49 ? lane : 48);
  // ---- phase 1: logit partials ----
  float4 acc = {0, 0, 0, 0};
#pragma unroll 8
  for (int i = 0; i < 64; ++i) {
    float4 x = pbase[i * 196];
    float wd = w_lds[d0 + i];
    acc.x += wd * x.x; acc.y += wd * x.y; acc.z += wd * x.z; acc.w += wd * x.w;
  }
  if (lane < 49) red[wv][lane] = acc;
  __syncthreads();
  // ---- wave 0: combine across waves, chunk softmax ----
  if (wv == 0) {
    float4 l4 = {0, 0, 0, 0};
    float lm = -1e30f;
    if (lane < 49) {
#pragma unroll
      for (int v8 = 0; v8 < 8; ++v8) {
        float4 r = red[v8][lane];
        l4.x += r.x; l4.y += r.y; l4.z += r.z; l4.w += r.w;
      }
      lm = fmaxf(fmaxf(l4.x, l4.y), fmaxf(l4.z, l4.w));
    }
    float m = wave_reduce_max(lm);
    float zs = 0.f;
    if (lane < 49) {
      float4 u4;
      u4.x = __expf(l4.x - m); u4.y = __expf(l4.y - m);
      u4.z = __expf(l4.z - m); u4.w = __expf(l4.w - m);
      zs = u4.x + u4.y + u4.z + u4.w;
      u_lds[lane] = u4;
    }
    float Z = wave_reduce_sum(zs);
    if (lane == 0) {
      mZ_part[((size_t)b * NCHK + c) * 2 + 0] = m;
      mZ_part[((size_t)b * NCHK + c) * 2 + 1] = Z;
    }
  }
  __syncthreads();
  // ---- phase 2: chunk-partial pooled (reads chunk again: L2/LLC resident) ----
  float4 u4 = {0, 0, 0, 0};
  if (lane < 49) u4 = u_lds[lane];
#pragma unroll 4
  for (int i = 0; i < 64; ++i) {
    float part = 0.f;
    if (lane < 49) {
      float4 x = pbase[i * 196];
      part = u4.x * x.x + u4.y * x.y + u4.z * x.z + u4.w * x.w;
    }
    part = wave_reduce_sum(part);
    if (lane == 0) p_s[d0 + i] = part;
  }
  P_part[((size_t)b * NCHK + c) * DD + d0 + lane] = p_s[d0 + lane];
}

// K5': combine chunk partials -> pooled[b,d].  grid (B), block 128 (float4 per thread).
__global__ void k5_combine(const float* __restrict__ P_part, const float* __restrict__ mZ_part,
                           float* __restrict__ pooled) {
  int b = blockIdx.x, t = threadIdx.x;
  float mc[NCHK], Zc[NCHK];
  float M = -1e30f;
#pragma unroll
  for (int c = 0; c < NCHK; ++c) {
    mc[c] = mZ_part[((size_t)b * NCHK + c) * 2 + 0];
    Zc[c] = mZ_part[((size_t)b * NCHK + c) * 2 + 1];
    M = fmaxf(M, mc[c]);
  }
  float Z = 0.f, al[NCHK];
#pragma unroll
  for (int c = 0; c < NCHK; ++c) { al[c] = __expf(mc[c] - M); Z += al[c] * Zc[c]; }
  float inv = 1.0f / Z;
  float4 s = {0, 0, 0, 0};
#pragma unroll
  for (int c = 0; c < NCHK; ++c) {
    float4 p = ((const float4*)P_part)[((size_t)b * NCHK + c) * 128 + t];
    s.x += al[c] * p.x; s.y += al[c] * p.y; s.z += al[c] * p.z; s.w += al[c] * p.w;
  }
  s.x *= inv; s.y *= inv; s.z *= inv; s.w *= inv;
  ((float4*)pooled)[(size_t)b * 128 + t] = s;
}

// K6: out[b,s] = pooled[b,:]·Wo[s,:] + bo[s]
// grid (32 s-chunks, B), block 256 (4 waves x 8 rows, unrolled)
__global__ void k6_out(const float* __restrict__ pooled, const float* __restrict__ Wo,
                       const float* __restrict__ bo, float* __restrict__ out) {
  __shared__ float p_s[DD];
  int b = blockIdx.y, t = threadIdx.x, lane = t & 63, wv = t >> 6;
  ((float2*)p_s)[t] = ((const float2*)(pooled + (size_t)b * DD))[t];
  __syncthreads();
  const float4* p4 = (const float4*)p_s;
  float4 p0 = p4[lane], p1 = p4[lane + 64];
  int s0 = blockIdx.x * 32 + wv * 8;
  float acc[8];
#pragma unroll
  for (int r = 0; r < 8; ++r) {
    const float4* wo4 = (const float4*)(Wo + (size_t)(s0 + r) * DD);
    float4 x0 = wo4[lane], x1 = wo4[lane + 64];
    acc[r] = x0.x * p0.x + x0.y * p0.y + x0.z * p0.z + x0.w * p0.w
           + x1.x * p1.x + x1.y * p1.y + x1.z * p1.z + x1.w * p1.w;
  }
#pragma unroll
  for (int r = 0; r < 8; ++r) acc[r] = wave_reduce_sum(acc[r]);
  if (lane == 0) {
#pragma unroll
    for (int r = 0; r < 8; ++r) out[(size_t)b * SS + s0 + r] = acc[r] + bo[s0 + r];
  }
}

extern "C" void kernel_launch(void* const* d_in, const int* in_sizes, int n_in,
                              void* d_out, int out_size, void* d_ws, size_t ws_size,
                              hipStream_t stream) {
  const float* in_state = (const float*)d_in[0];
  const float* image    = (const float*)d_in[1];
  const float* Wq       = (const float*)d_in[2];
  const float* bq       = (const float*)d_in[3];
  const float* Wc       = (const float*)d_in[4];
  const float* Wa       = (const float*)d_in[6];
  const float* Wo       = (const float*)d_in[8];
  const float* bo       = (const float*)d_in[9];
  float* out = (float*)d_out;

  // workspace layout (floats): ~1.6 MB total
  float* ws      = (float*)d_ws;
  float* v       = ws;                               // 2D           = 1024
  float* w       = v + 2 * DD;                       // B*D          = 65536
  float* P_part  = w + BB * DD;                      // B*NCHK*D     = 262144
  float* mZ_part = P_part + (size_t)BB * NCHK * DD;  // B*NCHK*2     = 1024
  float* pooled  = mZ_part + (size_t)BB * NCHK * 2;  // B*D          = 65536

  hipMemsetAsync(v, 0, 2 * DD * sizeof(float), stream);
  k1_v<<<dim3(4, 16), 256, 0, stream>>>(Wa, Wc, v);
  k2_w<<<dim3(16, BB), 256, 0, stream>>>(in_state, Wq, bq, v, w);
  k3_fused<<<dim3(NCHK, BB), 512, 0, stream>>>(image, w, P_part, mZ_part);
  k5_combine<<<BB, 128, 0, stream>>>(P_part, mZ_part, pooled);
  k6_out<<<dim3(32, BB), 256, 0, stream>>>(pooled, Wo, bo, out);
}